// Round 4
// baseline (609.526 us; speedup 1.0000x reference)
//
#include <hip/hip_runtime.h>
#include <math.h>
#include <float.h>

// Problem constants (match reference)
#define B_ 2048
#define D_ 512
#define T_ 16
#define H_ 1024
#define K_ 50
#define M_ 16
#define NSWEEP 2   // 2 round-robin sweeps: off-diag ~1e-2 -> output err ~1e-5 rel (tol 2e-2)

#define LDA_P 132  // As row stride (words); 132*4=528B = 33*16 -> float4-aligned rows
#define LDB_P 68   // Bs row stride; 68*4=272 = 17*16

__device__ __forceinline__ float bsum64(float v) {
  #pragma unroll
  for (int o = 1; o < 64; o <<= 1) v += __shfl_xor(v, o);
  return v;
}

// act[b,h] = sech^2(z) * W2[h],  z = concat(x,t)[b,:] @ W1[:,h] + b1[h]
// M=2048, N=1024, K=528. NN GEMM, 128x64 tile, 8x4 microtile, 256 threads.
__global__ __launch_bounds__(256)
void zact_kernel(const float* __restrict__ x, const float* __restrict__ t,
                 const float* __restrict__ W1, const float* __restrict__ b1,
                 const float* __restrict__ W2, float* __restrict__ act) {
  __shared__ float As[16 * LDA_P];
  __shared__ float Bs[16 * LDB_P];
  const int tid = threadIdx.x;
  const int tx = tid & 15, ty = tid >> 4;
  const int m0 = blockIdx.y * 128, n0 = blockIdx.x * 64;
  const int am = tid >> 2;            // 0..63: A-tile row (and row+64)
  const int ak = (tid & 3) * 4;       // k-quad within 16
  float acc[8][4] = {};
  for (int kb = 0; kb < 528; kb += 16) {
    float4 av0, av1, bv;
    if (kb < 512) {
      av0 = *(const float4*)(x + (size_t)(m0 + am) * 512 + kb + ak);
      av1 = *(const float4*)(x + (size_t)(m0 + 64 + am) * 512 + kb + ak);
    } else {  // last k-block: the treatment block (16 wide)
      av0 = *(const float4*)(t + (size_t)(m0 + am) * 16 + ak);
      av1 = *(const float4*)(t + (size_t)(m0 + 64 + am) * 16 + ak);
    }
    bv = *(const float4*)(W1 + (size_t)(kb + ty) * 1024 + n0 + tx * 4);
    __syncthreads();
    As[(ak + 0) * LDA_P + am] = av0.x;
    As[(ak + 1) * LDA_P + am] = av0.y;
    As[(ak + 2) * LDA_P + am] = av0.z;
    As[(ak + 3) * LDA_P + am] = av0.w;
    As[(ak + 0) * LDA_P + am + 64] = av1.x;
    As[(ak + 1) * LDA_P + am + 64] = av1.y;
    As[(ak + 2) * LDA_P + am + 64] = av1.z;
    As[(ak + 3) * LDA_P + am + 64] = av1.w;
    *(float4*)&Bs[ty * LDB_P + tx * 4] = bv;
    __syncthreads();
    #pragma unroll
    for (int kk = 0; kk < 16; kk++) {
      float4 a0 = *(const float4*)&As[kk * LDA_P + ty * 8];
      float4 a1 = *(const float4*)&As[kk * LDA_P + ty * 8 + 4];
      float4 b  = *(const float4*)&Bs[kk * LDB_P + tx * 4];
      const float av[8] = {a0.x, a0.y, a0.z, a0.w, a1.x, a1.y, a1.z, a1.w};
      const float bb[4] = {b.x, b.y, b.z, b.w};
      #pragma unroll
      for (int i = 0; i < 8; i++)
        #pragma unroll
        for (int j = 0; j < 4; j++)
          acc[i][j] += av[i] * bb[j];
    }
  }
  #pragma unroll
  for (int i = 0; i < 8; i++) {
    const int m = m0 + ty * 8 + i;
    float o[4];
    #pragma unroll
    for (int j = 0; j < 4; j++) {
      const int n = n0 + tx * 4 + j;
      float z = acc[i][j] + b1[n];
      // sech^2(z) = 4e/(1+e)^2, e = exp(-2|z|)  (overflow-free, even in z)
      float e = __builtin_amdgcn_exp2f(fabsf(z) * -2.885390082f);
      float r = __builtin_amdgcn_rcpf(1.f + e);
      o[j] = 4.f * e * r * r * W2[n];
    }
    *(float4*)(act + (size_t)m * 1024 + n0 + tx * 4) = *(float4*)o;
  }
}

// C[m,n] = sum_k A[m*lda+k] * Bt[n*ldb+k]  (NT GEMM, 128x64 tile, 8x4 micro)
__global__ __launch_bounds__(256)
void gemm_nt_kernel(const float* __restrict__ A, const float* __restrict__ Bt,
                    float* __restrict__ C, int N, int K, int lda, int ldb) {
  __shared__ float As[16 * LDA_P];
  __shared__ float Bs[16 * LDB_P];
  const int tid = threadIdx.x;
  const int tx = tid & 15, ty = tid >> 4;
  const int m0 = blockIdx.y * 128, n0 = blockIdx.x * 64;
  const int am = tid >> 2;
  const int ak = (tid & 3) * 4;
  float acc[8][4] = {};
  for (int kb = 0; kb < K; kb += 16) {
    float4 av0 = *(const float4*)(A + (size_t)(m0 + am) * lda + kb + ak);
    float4 av1 = *(const float4*)(A + (size_t)(m0 + 64 + am) * lda + kb + ak);
    float4 bv  = *(const float4*)(Bt + (size_t)(n0 + am) * ldb + kb + ak);
    __syncthreads();
    As[(ak + 0) * LDA_P + am] = av0.x;
    As[(ak + 1) * LDA_P + am] = av0.y;
    As[(ak + 2) * LDA_P + am] = av0.z;
    As[(ak + 3) * LDA_P + am] = av0.w;
    As[(ak + 0) * LDA_P + am + 64] = av1.x;
    As[(ak + 1) * LDA_P + am + 64] = av1.y;
    As[(ak + 2) * LDA_P + am + 64] = av1.z;
    As[(ak + 3) * LDA_P + am + 64] = av1.w;
    Bs[(ak + 0) * LDB_P + am] = bv.x;
    Bs[(ak + 1) * LDB_P + am] = bv.y;
    Bs[(ak + 2) * LDB_P + am] = bv.z;
    Bs[(ak + 3) * LDB_P + am] = bv.w;
    __syncthreads();
    #pragma unroll
    for (int kk = 0; kk < 16; kk++) {
      float4 a0 = *(const float4*)&As[kk * LDA_P + ty * 8];
      float4 a1 = *(const float4*)&As[kk * LDA_P + ty * 8 + 4];
      float4 b  = *(const float4*)&Bs[kk * LDB_P + tx * 4];
      const float av[8] = {a0.x, a0.y, a0.z, a0.w, a1.x, a1.y, a1.z, a1.w};
      const float bb[4] = {b.x, b.y, b.z, b.w};
      #pragma unroll
      for (int i = 0; i < 8; i++)
        #pragma unroll
        for (int j = 0; j < 4; j++)
          acc[i][j] += av[i] * bb[j];
    }
  }
  #pragma unroll
  for (int i = 0; i < 8; i++) {
    const int m = m0 + ty * 8 + i;
    float o[4] = {acc[i][0], acc[i][1], acc[i][2], acc[i][3]};
    *(float4*)(C + (size_t)m * N + n0 + tx * 4) = *(float4*)o;
  }
}

// sq[b] = sum_d P[b,d]^2
__global__ __launch_bounds__(64)
void sq_kernel(const float* __restrict__ P, float* __restrict__ sq) {
  const int b = blockIdx.x, lane = threadIdx.x;
  const float* pr = P + (size_t)b * 512;
  float s = 0.f;
  #pragma unroll
  for (int i = 0; i < 8; i++) { float v = pr[lane + i * 64]; s += v * v; }
  s = bsum64(s);
  if (lane == 0) sq[b] = s;
}

// Per row b: 50 smallest of d2[j] = sq[b]+sq[j]-2*G[b,j]  (the SET; order free)
__global__ __launch_bounds__(256)
void topk_kernel(const float* __restrict__ G, const float* __restrict__ sq,
                 int* __restrict__ idx) {
  const int b = blockIdx.x, tid = threadIdx.x;
  const int lane = tid & 63, wid = tid >> 6;
  float v[8];
  const float sqb = sq[b];
  #pragma unroll
  for (int i = 0; i < 8; i++) {
    int j = tid + i * 256;
    v[i] = sqb + sq[j] - 2.f * G[(size_t)b * 2048 + j];
  }
  __shared__ float swv[4];
  __shared__ int swi[4];
  __shared__ int chosen;
  for (int it = 0; it < K_; it++) {
    float bv = v[0]; int bj = tid;
    #pragma unroll
    for (int i = 1; i < 8; i++) {
      int j = tid + i * 256;
      if (v[i] < bv) { bv = v[i]; bj = j; }
    }
    #pragma unroll
    for (int o = 1; o < 64; o <<= 1) {
      float ov = __shfl_xor(bv, o);
      int oj = __shfl_xor(bj, o);
      if (ov < bv || (ov == bv && oj < bj)) { bv = ov; bj = oj; }
    }
    if (lane == 0) { swv[wid] = bv; swi[wid] = bj; }
    __syncthreads();
    if (tid == 0) {
      float mv = swv[0]; int mj = swi[0];
      for (int wn = 1; wn < 4; wn++) {
        if (swv[wn] < mv || (swv[wn] == mv && swi[wn] < mj)) { mv = swv[wn]; mj = swi[wn]; }
      }
      idx[b * K_ + it] = mj;
      chosen = mj;
    }
    __syncthreads();
    int cj = chosen;
    if ((cj & 255) == tid) v[cj >> 8] = FLT_MAX;
  }
}

// Per batch (one wave): S = double-centered 50x50 submatrix of G; one-sided
// Jacobi on columns (column c in lane c's registers); rotations applied to
// w = centered(C g) give J^T w; result = sum over top-16 col norms of w^2/lam.
__global__ __launch_bounds__(64, 2)
void final_kernel(const float* __restrict__ P, const float* __restrict__ grad,
                  const float* __restrict__ G, const int* __restrict__ idx,
                  float* __restrict__ out) {
  const int b = blockIdx.x;
  const int lane = threadIdx.x;
  __shared__ float red[K_ * 65];   // transpose-reduce scratch (stride 65: conflict-free)
  __shared__ int ids[K_];
  if (lane < K_) ids[lane] = idx[b * K_ + lane];
  __syncthreads();
  const int ac = (lane < K_) ? ids[lane] : 0;

  // gradient row in registers
  float g[8];
  #pragma unroll
  for (int i = 0; i < 8; i++) g[i] = grad[(size_t)b * 512 + lane + i * 64];

  // q_k = P[a_k].g: per-lane partials for ALL k (no serial butterflies),
  // then one LDS transpose reduce (lane k sums row k).
  for (int k = 0; k < K_; k++) {
    const float* pr = P + (size_t)ids[k] * 512;
    float s0 = 0.f, s1 = 0.f;
    #pragma unroll
    for (int i = 0; i < 8; i += 2) {
      s0 += pr[lane + i * 64] * g[i];
      s1 += pr[lane + (i + 1) * 64] * g[i + 1];
    }
    red[k * 65 + lane] = s0 + s1;
  }
  __syncthreads();
  float q = 0.f;
  if (lane < K_) {
    float s0 = 0.f, s1 = 0.f, s2 = 0.f, s3 = 0.f;
    const float* row = &red[lane * 65];
    #pragma unroll
    for (int j = 0; j < 64; j += 4) {
      s0 += row[j]; s1 += row[j + 1]; s2 += row[j + 2]; s3 += row[j + 3];
    }
    q = (s0 + s1) + (s2 + s3);
  }
  float qm = bsum64(lane < K_ ? q : 0.f) * (1.f / K_);
  float w = (lane < K_) ? (q - qm) : 0.f;

  // load column c of the 50x50 G-submatrix
  float f[K_];
  #pragma unroll
  for (int r = 0; r < K_; r++)
    f[r] = (lane < K_) ? G[(size_t)ids[r] * 2048 + ac] : 0.f;

  // double-centering (rowmean==colmean by symmetry)
  float cm = 0.f;
  #pragma unroll
  for (int r = 0; r < K_; r++) cm += f[r];
  cm *= (1.f / K_);
  float gs = bsum64(lane < K_ ? cm : 0.f) * (1.f / K_);
  float cs = cm - gs;
  #pragma unroll
  for (int r = 0; r < K_; r++) {
    float rm = __shfl(cm, r);
    if (lane < K_) f[r] -= rm + cs;
  }

  // column squared norm, tracked incrementally (exact norms recomputed after)
  float nrm = 0.f;
  #pragma unroll
  for (int r = 0; r < K_; r++) nrm += f[r] * f[r];

  // one-sided Hestenes Jacobi, round-robin (25 disjoint pairs/round)
  for (int sweep = 0; sweep < NSWEEP; sweep++) {
    for (int r = 0; r < 49; r++) {
      const int kk = (25 * r) % 49;
      int m;
      if (lane >= K_)      m = lane;
      else if (lane == 49) m = kk;
      else if (lane == kk) m = 49;
      else { m = (r - lane) % 49; if (m < 0) m += 49; }

      float y[K_];
      float d0 = 0.f, d1 = 0.f;
      #pragma unroll
      for (int r2 = 0; r2 < K_; r2 += 2) {
        y[r2]     = __shfl(f[r2], m);
        y[r2 + 1] = __shfl(f[r2 + 1], m);
        d0 += f[r2] * y[r2];
        d1 += f[r2 + 1] * y[r2 + 1];
      }
      float dot = d0 + d1;
      float onrm = __shfl(nrm, m);

      const bool isp = lane < m;
      float alpha = isp ? nrm : onrm;
      float beta  = isp ? onrm : nrm;
      // fast-approx rotation math (guarded below); ~1e-7 rel err is harmless here
      float tau = (beta - alpha) * 0.5f * __builtin_amdgcn_rcpf(dot);
      float sg = (tau >= 0.f) ? 1.f : -1.f;
      float s1 = __builtin_amdgcn_sqrtf(1.f + tau * tau);
      float tt = sg * __builtin_amdgcn_rcpf(fabsf(tau) + s1);
      float cc = __builtin_amdgcn_rsqf(1.f + tt * tt);
      float ssv = tt * cc;
      float sr = isp ? -ssv : ssv;
      if (lane >= K_ || fabsf(dot) < 1e-20f) { cc = 1.f; sr = 0.f; }
      #pragma unroll
      for (int r2 = 0; r2 < K_; r2++) f[r2] = cc * f[r2] + sr * y[r2];
      float yw = __shfl(w, m);
      w = cc * w + sr * yw;
      nrm = cc * cc * nrm + sr * sr * onrm + 2.f * cc * sr * dot;
    }
  }

  // eigenvalues = final column norms (S is PSD); top-16; sum w^2/lam
  float n2 = 0.f;
  #pragma unroll
  for (int r2 = 0; r2 < K_; r2++) n2 += f[r2] * f[r2];
  int rank = 0;
  #pragma unroll
  for (int j = 0; j < K_; j++) {
    float vj = __shfl(n2, j);
    rank += (vj > n2 || (vj == n2 && j < lane)) ? 1 : 0;
  }
  float lam = sqrtf(n2);
  float contrib = (lane < K_ && rank < M_) ? (w * w / lam) : 0.f;
  contrib = bsum64(contrib);
  if (lane == 0) atomicAdd(out, contrib * (1.f / B_));
}

extern "C" void kernel_launch(void* const* d_in, const int* in_sizes, int n_in,
                              void* d_out, int out_size, void* d_ws, size_t ws_size,
                              hipStream_t stream) {
  const float* x  = (const float*)d_in[0];
  const float* t  = (const float*)d_in[1];
  const float* P  = (const float*)d_in[2];
  const float* W1 = (const float*)d_in[3];
  const float* b1 = (const float*)d_in[4];
  const float* W2 = (const float*)d_in[5];
  // d_in[6] = b2: does not affect the gradient; unused.
  float* out = (float*)d_out;

  float* act  = (float*)d_ws;                 // 2048*1024
  float* grad = act + (size_t)B_ * H_;        // 2048*512
  float* G    = grad + (size_t)B_ * D_;       // 2048*2048
  float* sq   = G + (size_t)B_ * B_;          // 2048
  int*   idx  = (int*)(sq + B_);              // 2048*50

  hipMemsetAsync(d_out, 0, sizeof(float), stream);

  // grad_x = act @ W1[:512,:]^T  with act = sech^2(z)*W2
  zact_kernel<<<dim3(H_ / 64, B_ / 128), 256, 0, stream>>>(x, t, W1, b1, W2, act);
  gemm_nt_kernel<<<dim3(D_ / 64, B_ / 128), 256, 0, stream>>>(act, W1, grad, D_, H_, H_, H_);
  // pairwise Gram + kNN
  gemm_nt_kernel<<<dim3(B_ / 64, B_ / 128), 256, 0, stream>>>(P, P, G, B_, D_, D_, D_);
  sq_kernel<<<B_, 64, 0, stream>>>(P, sq);
  topk_kernel<<<B_, 256, 0, stream>>>(G, sq, idx);
  // per-batch spectral projection
  final_kernel<<<B_, 64, 0, stream>>>(P, grad, G, idx, out);
}

// Round 5
// 415.027 us; speedup vs baseline: 1.4686x; 1.4686x over previous
//
#include <hip/hip_runtime.h>
#include <math.h>
#include <float.h>

// Problem constants (match reference)
#define B_ 2048
#define D_ 512
#define T_ 16
#define H_ 1024
#define K_ 50
#define M_ 16
#define NSWEEP 2   // 2 round-robin sweeps (validated round 4: absmax ~0)

typedef __attribute__((ext_vector_type(8))) short s16x8;   // 8 bf16 (4 VGPRs)
typedef __attribute__((ext_vector_type(4))) float f32x4;   // MFMA accumulator

__device__ __forceinline__ float bsum64(float v) {
  #pragma unroll
  for (int o = 1; o < 64; o <<= 1) v += __shfl_xor(v, o);
  return v;
}

// ---- bf16 split helpers (RNE) ----
__device__ __forceinline__ unsigned bf16_rne(float v) {
  union { float f; unsigned u; } a; a.f = v;
  return (a.u + 0x7FFFu + ((a.u >> 16) & 1u)) >> 16;
}
__device__ __forceinline__ float bf16_val(unsigned h) {
  union { unsigned u; float f; } a; a.u = h << 16;
  return a.f;
}
__device__ __forceinline__ void split_bf16(float v, unsigned short* h, unsigned short* l) {
  unsigned hh = bf16_rne(v);
  *h = (unsigned short)hh;
  *l = (unsigned short)bf16_rne(v - bf16_val(hh));
}

// ---- conversion kernels ----
// xt[b, 0:512]=x, [512:528]=t, [528:544]=0   (K padded to 544 = 17*32)
__global__ __launch_bounds__(256)
void conv_xt(const float* __restrict__ x, const float* __restrict__ t,
             unsigned short* __restrict__ xh, unsigned short* __restrict__ xl) {
  const int b = blockIdx.y;
  const int c = blockIdx.x * 256 + threadIdx.x;
  if (c >= 544) return;
  float v = 0.f;
  if (c < 512) v = x[(size_t)b * 512 + c];
  else if (c < 528) v = t[(size_t)b * 16 + (c - 512)];
  unsigned short hh, ll; split_bf16(v, &hh, &ll);
  xh[(size_t)b * 544 + c] = hh;
  xl[(size_t)b * 544 + c] = ll;
}

// straight element-wise split (W1 and P)
__global__ __launch_bounds__(256)
void conv_mat(const float* __restrict__ A, unsigned short* __restrict__ h,
              unsigned short* __restrict__ l, int n) {
  int i = blockIdx.x * 256 + threadIdx.x;
  if (i >= n) return;
  unsigned short hh, ll; split_bf16(A[i], &hh, &ll);
  h[i] = hh; l[i] = ll;
}

// w1t[h, k] = W1[k, h], k padded 528->544 with zeros.  32x32 LDS tile transpose.
__global__ __launch_bounds__(256)
void conv_w1t(const float* __restrict__ W1, unsigned short* __restrict__ th,
              unsigned short* __restrict__ tl) {
  __shared__ float tile[32][33];
  const int tx = threadIdx.x & 31, ty = threadIdx.x >> 5;   // 32 x 8
  const int kb = blockIdx.x * 32, hb = blockIdx.y * 32;
  #pragma unroll
  for (int j = 0; j < 4; j++) {
    int k = kb + ty + j * 8;
    tile[ty + j * 8][tx] = (k < 528) ? W1[(size_t)k * 1024 + hb + tx] : 0.f;
  }
  __syncthreads();
  #pragma unroll
  for (int j = 0; j < 4; j++) {
    int hrow = hb + ty + j * 8;
    float v = tile[tx][ty + j * 8];
    unsigned short hh, ll; split_bf16(v, &hh, &ll);
    th[(size_t)hrow * 544 + kb + tx] = hh;
    tl[(size_t)hrow * 544 + kb + tx] = ll;
  }
}

// ---- split-bf16 MFMA NT GEMM ----
// C[m,n] = sum_k A[m,k]*B[n,k], A=[M,lda] B=[N,ldb] bf16 hi/lo pairs.
// 3 passes (hi*hi + hi*lo + lo*hi) recover ~fp32 accuracy (lo*lo ~2^-18 dropped).
// Tile 64x64, 4 waves of 32x32, K-step 32. EPI=1: zact epilogue -> bf16-split act.
template <int EPI>
__global__ __launch_bounds__(256)
void mfma_nt(const unsigned short* __restrict__ Ah, const unsigned short* __restrict__ Al, int lda,
             const unsigned short* __restrict__ Bh, const unsigned short* __restrict__ Bl, int ldb,
             int K, float* __restrict__ C, int ldc,
             const float* __restrict__ b1, const float* __restrict__ W2,
             unsigned short* __restrict__ acth, unsigned short* __restrict__ actl) {
  // row stride 40 shorts (80B): 16B-aligned rows, frag reads land 2-way (free)
  __shared__ unsigned short sAh[64 * 40], sAl[64 * 40], sBh[64 * 40], sBl[64 * 40];
  const int tid = threadIdx.x;
  const int lane = tid & 63, wv = tid >> 6;
  const int wm = wv >> 1, wn = wv & 1;
  const int lr = lane & 15, lq = lane >> 4;
  const int m0 = blockIdx.y * 64, n0 = blockIdx.x * 64;
  const int srow = tid >> 2, sk = (tid & 3) * 8;   // staging: 64 rows x 4 k-octets
  f32x4 acc[2][2];
  #pragma unroll
  for (int mt = 0; mt < 2; mt++)
    #pragma unroll
    for (int nt = 0; nt < 2; nt++)
      #pragma unroll
      for (int i = 0; i < 4; i++) acc[mt][nt][i] = 0.f;

  for (int kb = 0; kb < K; kb += 32) {
    float4 va = *(const float4*)(Ah + (size_t)(m0 + srow) * lda + kb + sk);
    float4 vb = *(const float4*)(Al + (size_t)(m0 + srow) * lda + kb + sk);
    float4 vc = *(const float4*)(Bh + (size_t)(n0 + srow) * ldb + kb + sk);
    float4 vd = *(const float4*)(Bl + (size_t)(n0 + srow) * ldb + kb + sk);
    __syncthreads();
    *(float4*)&sAh[srow * 40 + sk] = va;
    *(float4*)&sAl[srow * 40 + sk] = vb;
    *(float4*)&sBh[srow * 40 + sk] = vc;
    *(float4*)&sBl[srow * 40 + sk] = vd;
    __syncthreads();
    s16x8 fah[2], fal[2], fbh[2], fbl[2];
    #pragma unroll
    for (int mt = 0; mt < 2; mt++) {
      const int r = wm * 32 + mt * 16 + lr;          // A row (m), 8 contiguous k at lq*8
      fah[mt] = *(const s16x8*)&sAh[r * 40 + lq * 8];
      fal[mt] = *(const s16x8*)&sAl[r * 40 + lq * 8];
    }
    #pragma unroll
    for (int nt = 0; nt < 2; nt++) {
      const int r = wn * 32 + nt * 16 + lr;          // B row (n), 8 contiguous k
      fbh[nt] = *(const s16x8*)&sBh[r * 40 + lq * 8];
      fbl[nt] = *(const s16x8*)&sBl[r * 40 + lq * 8];
    }
    #pragma unroll
    for (int mt = 0; mt < 2; mt++)
      #pragma unroll
      for (int nt = 0; nt < 2; nt++)
        acc[mt][nt] = __builtin_amdgcn_mfma_f32_16x16x32_bf16(fah[mt], fbh[nt], acc[mt][nt], 0, 0, 0);
    #pragma unroll
    for (int mt = 0; mt < 2; mt++)
      #pragma unroll
      for (int nt = 0; nt < 2; nt++)
        acc[mt][nt] = __builtin_amdgcn_mfma_f32_16x16x32_bf16(fah[mt], fbl[nt], acc[mt][nt], 0, 0, 0);
    #pragma unroll
    for (int mt = 0; mt < 2; mt++)
      #pragma unroll
      for (int nt = 0; nt < 2; nt++)
        acc[mt][nt] = __builtin_amdgcn_mfma_f32_16x16x32_bf16(fal[mt], fbh[nt], acc[mt][nt], 0, 0, 0);
  }

  // C/D layout: row=(lane>>4)*4+reg, col=lane&15  [verified m89/m91]
  #pragma unroll
  for (int nt = 0; nt < 2; nt++) {
    const int n = n0 + wn * 32 + nt * 16 + lr;
    float bb = 0.f, ww = 0.f;
    if (EPI == 1) { bb = b1[n]; ww = W2[n]; }
    #pragma unroll
    for (int mt = 0; mt < 2; mt++) {
      #pragma unroll
      for (int r = 0; r < 4; r++) {
        const int m = m0 + wm * 32 + mt * 16 + lq * 4 + r;
        float v = acc[mt][nt][r];
        if (EPI == 0) {
          C[(size_t)m * ldc + n] = v;
        } else {
          float z = v + bb;
          // sech^2(z) = 4e/(1+e)^2, e = exp(-2|z|)
          float e = __builtin_amdgcn_exp2f(fabsf(z) * -2.885390082f);
          float rc = __builtin_amdgcn_rcpf(1.f + e);
          float s = 4.f * e * rc * rc * ww;
          unsigned short hh, ll; split_bf16(s, &hh, &ll);
          acth[(size_t)m * ldc + n] = hh;
          actl[(size_t)m * ldc + n] = ll;
        }
      }
    }
  }
}

// sq[b] = sum_d P[b,d]^2
__global__ __launch_bounds__(64)
void sq_kernel(const float* __restrict__ P, float* __restrict__ sq) {
  const int b = blockIdx.x, lane = threadIdx.x;
  const float* pr = P + (size_t)b * 512;
  float s = 0.f;
  #pragma unroll
  for (int i = 0; i < 8; i++) { float v = pr[lane + i * 64]; s += v * v; }
  s = bsum64(s);
  if (lane == 0) sq[b] = s;
}

// Per row b: 50 smallest of d2[j] = sq[b]+sq[j]-2*G[b,j]  (the SET; order free)
__global__ __launch_bounds__(256)
void topk_kernel(const float* __restrict__ G, const float* __restrict__ sq,
                 int* __restrict__ idx) {
  const int b = blockIdx.x, tid = threadIdx.x;
  const int lane = tid & 63, wid = tid >> 6;
  float v[8];
  const float sqb = sq[b];
  #pragma unroll
  for (int i = 0; i < 8; i++) {
    int j = tid + i * 256;
    v[i] = sqb + sq[j] - 2.f * G[(size_t)b * 2048 + j];
  }
  __shared__ float swv[4];
  __shared__ int swi[4];
  __shared__ int chosen;
  for (int it = 0; it < K_; it++) {
    float bv = v[0]; int bj = tid;
    #pragma unroll
    for (int i = 1; i < 8; i++) {
      int j = tid + i * 256;
      if (v[i] < bv) { bv = v[i]; bj = j; }
    }
    #pragma unroll
    for (int o = 1; o < 64; o <<= 1) {
      float ov = __shfl_xor(bv, o);
      int oj = __shfl_xor(bj, o);
      if (ov < bv || (ov == bv && oj < bj)) { bv = ov; bj = oj; }
    }
    if (lane == 0) { swv[wid] = bv; swi[wid] = bj; }
    __syncthreads();
    if (tid == 0) {
      float mv = swv[0]; int mj = swi[0];
      for (int wn = 1; wn < 4; wn++) {
        if (swv[wn] < mv || (swv[wn] == mv && swi[wn] < mj)) { mv = swv[wn]; mj = swi[wn]; }
      }
      idx[b * K_ + it] = mj;
      chosen = mj;
    }
    __syncthreads();
    int cj = chosen;
    if ((cj & 255) == tid) v[cj >> 8] = FLT_MAX;
  }
}

// Per batch (one wave): S = double-centered 50x50 submatrix of G; one-sided
// Jacobi on columns (column c in lane c's registers); rotations applied to
// w = centered(C g) give J^T w; result = sum over top-16 col norms of w^2/lam.
__global__ __launch_bounds__(64, 2)
void final_kernel(const float* __restrict__ P, const float* __restrict__ grad,
                  const float* __restrict__ G, const int* __restrict__ idx,
                  float* __restrict__ out) {
  const int b = blockIdx.x;
  const int lane = threadIdx.x;
  __shared__ float red[K_ * 65];   // transpose-reduce scratch (stride 65: conflict-free)
  __shared__ int ids[K_];
  if (lane < K_) ids[lane] = idx[b * K_ + lane];
  __syncthreads();
  const int ac = (lane < K_) ? ids[lane] : 0;

  float g[8];
  #pragma unroll
  for (int i = 0; i < 8; i++) g[i] = grad[(size_t)b * 512 + lane + i * 64];

  // q_k = P[a_k].g via per-lane partials + one LDS transpose reduce
  for (int k = 0; k < K_; k++) {
    const float* pr = P + (size_t)ids[k] * 512;
    float s0 = 0.f, s1 = 0.f;
    #pragma unroll
    for (int i = 0; i < 8; i += 2) {
      s0 += pr[lane + i * 64] * g[i];
      s1 += pr[lane + (i + 1) * 64] * g[i + 1];
    }
    red[k * 65 + lane] = s0 + s1;
  }
  __syncthreads();
  float q = 0.f;
  if (lane < K_) {
    float s0 = 0.f, s1 = 0.f, s2 = 0.f, s3 = 0.f;
    const float* row = &red[lane * 65];
    #pragma unroll
    for (int j = 0; j < 64; j += 4) {
      s0 += row[j]; s1 += row[j + 1]; s2 += row[j + 2]; s3 += row[j + 3];
    }
    q = (s0 + s1) + (s2 + s3);
  }
  float qm = bsum64(lane < K_ ? q : 0.f) * (1.f / K_);
  float w = (lane < K_) ? (q - qm) : 0.f;

  float f[K_];
  #pragma unroll
  for (int r = 0; r < K_; r++)
    f[r] = (lane < K_) ? G[(size_t)ids[r] * 2048 + ac] : 0.f;

  // double-centering (rowmean==colmean by symmetry)
  float cm = 0.f;
  #pragma unroll
  for (int r = 0; r < K_; r++) cm += f[r];
  cm *= (1.f / K_);
  float gs = bsum64(lane < K_ ? cm : 0.f) * (1.f / K_);
  float cs = cm - gs;
  #pragma unroll
  for (int r = 0; r < K_; r++) {
    float rm = __shfl(cm, r);
    if (lane < K_) f[r] -= rm + cs;
  }

  float nrm = 0.f;
  #pragma unroll
  for (int r = 0; r < K_; r++) nrm += f[r] * f[r];

  // one-sided Hestenes Jacobi, round-robin (25 disjoint pairs/round)
  for (int sweep = 0; sweep < NSWEEP; sweep++) {
    for (int r = 0; r < 49; r++) {
      const int kk = (25 * r) % 49;
      int m;
      if (lane >= K_)      m = lane;
      else if (lane == 49) m = kk;
      else if (lane == kk) m = 49;
      else { m = (r - lane) % 49; if (m < 0) m += 49; }

      float y[K_];
      float d0 = 0.f, d1 = 0.f, d2 = 0.f, d3 = 0.f;
      #pragma unroll
      for (int r2 = 0; r2 < 48; r2 += 4) {
        y[r2]     = __shfl(f[r2], m);
        y[r2 + 1] = __shfl(f[r2 + 1], m);
        y[r2 + 2] = __shfl(f[r2 + 2], m);
        y[r2 + 3] = __shfl(f[r2 + 3], m);
        d0 += f[r2] * y[r2];
        d1 += f[r2 + 1] * y[r2 + 1];
        d2 += f[r2 + 2] * y[r2 + 2];
        d3 += f[r2 + 3] * y[r2 + 3];
      }
      y[48] = __shfl(f[48], m);
      y[49] = __shfl(f[49], m);
      d0 += f[48] * y[48];
      d1 += f[49] * y[49];
      float dot = (d0 + d1) + (d2 + d3);
      float onrm = __shfl(nrm, m);

      const bool isp = lane < m;
      float alpha = isp ? nrm : onrm;
      float beta  = isp ? onrm : nrm;
      float tau = (beta - alpha) * 0.5f * __builtin_amdgcn_rcpf(dot);
      float sg = (tau >= 0.f) ? 1.f : -1.f;
      float s1 = __builtin_amdgcn_sqrtf(1.f + tau * tau);
      float tt = sg * __builtin_amdgcn_rcpf(fabsf(tau) + s1);
      float cc = __builtin_amdgcn_rsqf(1.f + tt * tt);
      float ssv = tt * cc;
      float sr = isp ? -ssv : ssv;
      if (lane >= K_ || fabsf(dot) < 1e-20f) { cc = 1.f; sr = 0.f; }
      #pragma unroll
      for (int r2 = 0; r2 < K_; r2++) f[r2] = cc * f[r2] + sr * y[r2];
      float yw = __shfl(w, m);
      w = cc * w + sr * yw;
      nrm = cc * cc * nrm + sr * sr * onrm + 2.f * cc * sr * dot;
    }
  }

  float n2 = 0.f;
  #pragma unroll
  for (int r2 = 0; r2 < K_; r2++) n2 += f[r2] * f[r2];
  int rank = 0;
  #pragma unroll
  for (int j = 0; j < K_; j++) {
    float vj = __shfl(n2, j);
    rank += (vj > n2 || (vj == n2 && j < lane)) ? 1 : 0;
  }
  float lam = sqrtf(n2);
  float contrib = (lane < K_ && rank < M_) ? (w * w / lam) : 0.f;
  contrib = bsum64(contrib);
  if (lane == 0) atomicAdd(out, contrib * (1.f / B_));
}

extern "C" void kernel_launch(void* const* d_in, const int* in_sizes, int n_in,
                              void* d_out, int out_size, void* d_ws, size_t ws_size,
                              hipStream_t stream) {
  const float* x  = (const float*)d_in[0];
  const float* t  = (const float*)d_in[1];
  const float* P  = (const float*)d_in[2];
  const float* W1 = (const float*)d_in[3];
  const float* b1 = (const float*)d_in[4];
  const float* W2 = (const float*)d_in[5];
  // d_in[6] = b2: does not affect the gradient; unused.
  float* out = (float*)d_out;

  // workspace layout (~41 MB, all segments 16B-aligned)
  float* G    = (float*)d_ws;                       // 2048*2048 f32
  float* grad = G + (size_t)B_ * B_;                // 2048*512 f32
  float* sq   = grad + (size_t)B_ * D_;             // 2048 f32
  int*   idx  = (int*)(sq + B_);                    // 2048*50 i32
  unsigned short* xt_h  = (unsigned short*)(idx + B_ * K_);
  unsigned short* xt_l  = xt_h  + (size_t)B_ * 544;
  unsigned short* w1t_h = xt_l  + (size_t)B_ * 544;   // [1024][544]
  unsigned short* w1t_l = w1t_h + (size_t)H_ * 544;
  unsigned short* w1_h  = w1t_l + (size_t)H_ * 544;   // [528][1024]
  unsigned short* w1_l  = w1_h  + (size_t)528 * H_;
  unsigned short* p_h   = w1_l  + (size_t)528 * H_;   // [2048][512]
  unsigned short* p_l   = p_h   + (size_t)B_ * D_;
  unsigned short* act_h = p_l   + (size_t)B_ * D_;    // [2048][1024]
  unsigned short* act_l = act_h + (size_t)B_ * H_;

  hipMemsetAsync(d_out, 0, sizeof(float), stream);

  // bf16 hi/lo conversions
  conv_xt<<<dim3(3, B_), 256, 0, stream>>>(x, t, xt_h, xt_l);
  conv_w1t<<<dim3(17, 32), 256, 0, stream>>>(W1, w1t_h, w1t_l);
  conv_mat<<<(528 * H_ + 255) / 256, 256, 0, stream>>>(W1, w1_h, w1_l, 528 * H_);
  conv_mat<<<(B_ * D_ + 255) / 256, 256, 0, stream>>>(P, p_h, p_l, B_ * D_);

  // act = sech^2(xt@W1 + b1) * W2   (bf16-split output, fused epilogue)
  mfma_nt<1><<<dim3(H_ / 64, B_ / 64), 256, 0, stream>>>(
      xt_h, xt_l, 544, w1t_h, w1t_l, 544, 544,
      nullptr, H_, b1, W2, act_h, act_l);
  // grad[b,d] = sum_h act[b,h] * W1[d,h]
  mfma_nt<0><<<dim3(D_ / 64, B_ / 64), 256, 0, stream>>>(
      act_h, act_l, H_, w1_h, w1_l, H_, H_,
      grad, D_, nullptr, nullptr, nullptr, nullptr);
  // G = P @ P^T
  mfma_nt<0><<<dim3(B_ / 64, B_ / 64), 256, 0, stream>>>(
      p_h, p_l, D_, p_h, p_l, D_, D_,
      G, B_, nullptr, nullptr, nullptr, nullptr);

  sq_kernel<<<B_, 64, 0, stream>>>(P, sq);
  topk_kernel<<<B_, 256, 0, stream>>>(G, sq, idx);
  final_kernel<<<B_, 64, 0, stream>>>(P, grad, G, idx, out);
}